// Round 1
// baseline (84.602 us; speedup 1.0000x reference)
//
#include <hip/hip_runtime.h>
#include <hip/hip_bf16.h>

#define N_FIELDS 8
#define VOCAB    12
#define DIM      64
#define BATCH    131072
#define N_PAIRS  28            // 8 choose 2
#define G_FLOATS (N_PAIRS * VOCAB * VOCAB)   // 4032
#define C_FLOATS (2 * N_FIELDS * VOCAB)      // 192
#define WS_FLOATS (G_FLOATS + C_FLOATS)      // 4224

// output layout: inferences [0, 262144), loss [262144], pair [262145, 393217)
#define OUT_LOSS 262144
#define OUT_PAIR 262145

__device__ __constant__ unsigned char PF[N_PAIRS] =
    {0,0,0,0,0,0,0, 1,1,1,1,1,1, 2,2,2,2,2, 3,3,3,3, 4,4,4, 5,5, 6};
__device__ __constant__ unsigned char PG[N_PAIRS] =
    {1,2,3,4,5,6,7, 2,3,4,5,6,7, 3,4,5,6,7, 4,5,6,7, 5,6,7, 6,7, 7};

// Kernel 1: build gram + combined first-order/action tables in d_ws, zero loss.
__global__ __launch_bounds__(256) void fm_precompute(
    const float* __restrict__ emb,        // (8,12,64)
    const float* __restrict__ emb_first,  // (8,12,1)
    const float* __restrict__ act_emb,    // (2,64)
    const float* __restrict__ act_first,  // (2,1)
    float* __restrict__ ws,
    float* __restrict__ out) {
  int j = blockIdx.x * 256 + threadIdx.x;
  if (j == 0) out[OUT_LOSS] = 0.0f;
  if (j < G_FLOATS) {
    // G[p][vf][vg] = dot(E[f][vf], E[g][vg])
    int p  = j / (VOCAB * VOCAB);
    int r  = j - p * (VOCAB * VOCAB);
    int vf = r / VOCAB;
    int vg = r - vf * VOCAB;
    int f = PF[p], g = PG[p];
    const float4* A = (const float4*)(emb + (f * VOCAB + vf) * DIM);
    const float4* B = (const float4*)(emb + (g * VOCAB + vg) * DIM);
    float s = 0.0f;
#pragma unroll
    for (int k = 0; k < DIM / 4; ++k) {
      float4 a = A[k], b = B[k];
      s += a.x * b.x + a.y * b.y + a.z * b.z + a.w * b.w;
    }
    ws[j] = s;
  } else if (j < WS_FLOATS) {
    // C[a][f][v] = dot(E[f][v], act_emb[a]) + emb_first[f][v] + act_first[a]/8
    int jj = j - G_FLOATS;
    int a  = jj / (N_FIELDS * VOCAB);
    int r  = jj - a * (N_FIELDS * VOCAB);     // f*12 + v
    const float4* A = (const float4*)(emb + r * DIM);
    const float4* B = (const float4*)(act_emb + a * DIM);
    float s = 0.0f;
#pragma unroll
    for (int k = 0; k < DIM / 4; ++k) {
      float4 x = A[k], y = B[k];
      s += x.x * y.x + x.y * y.y + x.z * y.z + x.w * y.w;
    }
    s += emb_first[r] + act_first[a] * 0.125f;
    ws[j] = s;
  }
}

// Kernel 2: one thread per sample.
__global__ __launch_bounds__(256) void fm_main(
    const float* __restrict__ ws,
    const float* __restrict__ label,
    const float* __restrict__ pw,
    const int*   __restrict__ feats,
    float* __restrict__ out) {
  __shared__ float lds[WS_FLOATS];
  __shared__ float red[4];
  int tid = threadIdx.x;
  // stage tables: 4224 floats, coalesced
#pragma unroll
  for (int j = tid; j < WS_FLOATS; j += 256) lds[j] = ws[j];
  __syncthreads();

  int i = blockIdx.x * 256 + tid;

  int v[N_FIELDS];
#pragma unroll
  for (int f = 0; f < N_FIELDS; ++f) v[f] = feats[f * BATCH + i];
  int m[N_FIELDS];
#pragma unroll
  for (int f = 0; f < N_FIELDS; ++f) m[f] = v[f] * VOCAB;

  // pair interaction: sum over 28 field pairs of G[p][vf][vg]
  float pairsum = 0.0f;
  {
    int p = 0;
#pragma unroll
    for (int f = 0; f < N_FIELDS; ++f) {
#pragma unroll
      for (int g = f + 1; g < N_FIELDS; ++g) {
        pairsum += lds[p * (VOCAB * VOCAB) + m[f] + v[g]];
        ++p;
      }
    }
  }

  // inferences
  float inf0 = 0.0f, inf1 = 0.0f;
#pragma unroll
  for (int f = 0; f < N_FIELDS; ++f) {
    inf0 += lds[G_FLOATS            + f * VOCAB + v[f]];
    inf1 += lds[G_FLOATS + N_FIELDS * VOCAB + f * VOCAB + v[f]];
  }

  float2 l = ((const float2*)label)[i];
  float2 w = ((const float2*)pw)[i];
  float d0 = inf0 - l.x, d1 = inf1 - l.y;
  float lw = w.x * d0 * d0 + w.y * d1 * d1;

  ((float2*)out)[i] = make_float2(inf0, inf1);
  out[OUT_PAIR + i] = pairsum;

  // loss reduction: wave shuffle -> LDS -> one atomic per block
#pragma unroll
  for (int off = 32; off > 0; off >>= 1) lw += __shfl_down(lw, off, 64);
  int lane = tid & 63, wid = tid >> 6;
  if (lane == 0) red[wid] = lw;
  __syncthreads();
  if (tid == 0) {
    float s = red[0] + red[1] + red[2] + red[3];
    atomicAdd(out + OUT_LOSS, s * (1.0f / (float)BATCH));
  }
}

extern "C" void kernel_launch(void* const* d_in, const int* in_sizes, int n_in,
                              void* d_out, int out_size, void* d_ws, size_t ws_size,
                              hipStream_t stream) {
  const float* emb       = (const float*)d_in[0];  // (8,12,64)
  const float* emb_first = (const float*)d_in[1];  // (8,12,1)
  const float* act_emb   = (const float*)d_in[2];  // (2,64)
  const float* act_first = (const float*)d_in[3];  // (2,1)
  const float* label     = (const float*)d_in[4];  // (131072,2)
  const float* pw        = (const float*)d_in[5];  // (131072,2)
  const int*   feats     = (const int*)d_in[6];    // (8,131072)
  float* out = (float*)d_out;
  float* ws  = (float*)d_ws;

  fm_precompute<<<(WS_FLOATS + 255) / 256, 256, 0, stream>>>(
      emb, emb_first, act_emb, act_first, ws, out);
  fm_main<<<BATCH / 256, 256, 0, stream>>>(ws, label, pw, feats, out);
}

// Round 2
// 82.985 us; speedup vs baseline: 1.0195x; 1.0195x over previous
//
#include <hip/hip_runtime.h>
#include <hip/hip_bf16.h>

#define N_FIELDS 8
#define VOCAB    12
#define DIM      64
#define BATCH    131072
#define N_PAIRS  28            // 8 choose 2
#define G_FLOATS (N_PAIRS * VOCAB * VOCAB)   // 4032
#define C_FLOATS (2 * N_FIELDS * VOCAB)      // 192 (stored interleaved: [f*12+v][a])
#define WS_FLOATS (G_FLOATS + C_FLOATS)      // 4224
#define WS_VEC4  (WS_FLOATS / 4)             // 1056

// output layout: inferences [0, 262144), loss [262144], pair [262145, 393217)
#define OUT_LOSS 262144
#define OUT_PAIR 262145

__device__ __constant__ unsigned char PF[N_PAIRS] =
    {0,0,0,0,0,0,0, 1,1,1,1,1,1, 2,2,2,2,2, 3,3,3,3, 4,4,4, 5,5, 6};
__device__ __constant__ unsigned char PG[N_PAIRS] =
    {1,2,3,4,5,6,7, 2,3,4,5,6,7, 3,4,5,6,7, 4,5,6,7, 5,6,7, 6,7, 7};

// Kernel 1: build gram table G[p][vf][vg] and interleaved C2[(f,v)][a] in d_ws.
__global__ __launch_bounds__(256) void fm_precompute(
    const float* __restrict__ emb,        // (8,12,64)
    const float* __restrict__ emb_first,  // (8,12,1)
    const float* __restrict__ act_emb,    // (2,64)
    const float* __restrict__ act_first,  // (2,1)
    float* __restrict__ ws,
    float* __restrict__ out) {
  int j = blockIdx.x * 256 + threadIdx.x;
  if (j == 0) out[OUT_LOSS] = 0.0f;
  if (j < G_FLOATS) {
    // G[p][vf][vg] = dot(E[f][vf], E[g][vg])
    int p  = j / (VOCAB * VOCAB);
    int r  = j - p * (VOCAB * VOCAB);
    int vf = r / VOCAB;
    int vg = r - vf * VOCAB;
    int f = PF[p], g = PG[p];
    const float4* A = (const float4*)(emb + (f * VOCAB + vf) * DIM);
    const float4* B = (const float4*)(emb + (g * VOCAB + vg) * DIM);
    float s = 0.0f;
#pragma unroll
    for (int k = 0; k < DIM / 4; ++k) {
      float4 a = A[k], b = B[k];
      s += a.x * b.x + a.y * b.y + a.z * b.z + a.w * b.w;
    }
    ws[j] = s;
  } else if (j < WS_FLOATS) {
    // C2[e][a] = dot(E[e], act_emb[a]) + emb_first[e] + act_first[a]/8
    // stored interleaved: ws[G_FLOATS + e*2 + a], e = f*12+v
    int jj = j - G_FLOATS;            // = e*2 + a
    int a  = jj & 1;
    int e  = jj >> 1;
    const float4* A = (const float4*)(emb + e * DIM);
    const float4* B = (const float4*)(act_emb + a * DIM);
    float s = 0.0f;
#pragma unroll
    for (int k = 0; k < DIM / 4; ++k) {
      float4 x = A[k], y = B[k];
      s += x.x * y.x + x.y * y.y + x.z * y.z + x.w * y.w;
    }
    s += emb_first[e] + act_first[a] * 0.125f;
    ws[j] = s;
  }
}

// Kernel 2: one thread per sample.
__global__ __launch_bounds__(256) void fm_main(
    const float4* __restrict__ ws4,
    const float* __restrict__ label,
    const float* __restrict__ pw,
    const int*   __restrict__ feats,
    float* __restrict__ out) {
  __shared__ float4 lds4[WS_VEC4];
  __shared__ float red[4];
  float* lds = (float*)lds4;
  int tid = threadIdx.x;
  // stage tables: 1056 float4s, coalesced 16B/lane
  for (int j = tid; j < WS_VEC4; j += 256) lds4[j] = ws4[j];
  __syncthreads();

  int i = blockIdx.x * 256 + tid;

  int v[N_FIELDS];
#pragma unroll
  for (int f = 0; f < N_FIELDS; ++f) v[f] = feats[f * BATCH + i];
  int m[N_FIELDS];
#pragma unroll
  for (int f = 0; f < N_FIELDS; ++f) m[f] = v[f] * VOCAB;

  // pair interaction: sum over 28 field pairs of G[p][vf][vg]
  float pairsum = 0.0f;
  {
    int p = 0;
#pragma unroll
    for (int f = 0; f < N_FIELDS; ++f) {
#pragma unroll
      for (int g = f + 1; g < N_FIELDS; ++g) {
        pairsum += lds[p * (VOCAB * VOCAB) + m[f] + v[g]];
        ++p;
      }
    }
  }

  // inferences: 8 x ds_read_b64 from interleaved C2
  const float2* C2 = (const float2*)(lds + G_FLOATS);
  float inf0 = 0.0f, inf1 = 0.0f;
#pragma unroll
  for (int f = 0; f < N_FIELDS; ++f) {
    float2 c = C2[f * VOCAB + v[f]];
    inf0 += c.x;
    inf1 += c.y;
  }

  float2 l = ((const float2*)label)[i];
  float2 w = ((const float2*)pw)[i];
  float d0 = inf0 - l.x, d1 = inf1 - l.y;
  float lw = w.x * d0 * d0 + w.y * d1 * d1;

  ((float2*)out)[i] = make_float2(inf0, inf1);
  out[OUT_PAIR + i] = pairsum;

  // loss reduction: wave shuffle -> LDS -> one atomic per block
#pragma unroll
  for (int off = 32; off > 0; off >>= 1) lw += __shfl_down(lw, off, 64);
  int lane = tid & 63, wid = tid >> 6;
  if (lane == 0) red[wid] = lw;
  __syncthreads();
  if (tid == 0) {
    float s = red[0] + red[1] + red[2] + red[3];
    atomicAdd(out + OUT_LOSS, s * (1.0f / (float)BATCH));
  }
}

extern "C" void kernel_launch(void* const* d_in, const int* in_sizes, int n_in,
                              void* d_out, int out_size, void* d_ws, size_t ws_size,
                              hipStream_t stream) {
  const float* emb       = (const float*)d_in[0];  // (8,12,64)
  const float* emb_first = (const float*)d_in[1];  // (8,12,1)
  const float* act_emb   = (const float*)d_in[2];  // (2,64)
  const float* act_first = (const float*)d_in[3];  // (2,1)
  const float* label     = (const float*)d_in[4];  // (131072,2)
  const float* pw        = (const float*)d_in[5];  // (131072,2)
  const int*   feats     = (const int*)d_in[6];    // (8,131072)
  float* out = (float*)d_out;
  float* ws  = (float*)d_ws;

  fm_precompute<<<(WS_FLOATS + 255) / 256, 256, 0, stream>>>(
      emb, emb_first, act_emb, act_first, ws, out);
  fm_main<<<BATCH / 256, 256, 0, stream>>>(
      (const float4*)ws, label, pw, feats, out);
}